// Round 9
// baseline (2431.610 us; speedup 1.0000x reference)
//
#include <hip/hip_runtime.h>
#include <cstdint>
#include <cstddef>

#define BATCH 128
#define TLEN 4096
#define KS 64
#define NCHUNK 64  // chunk c covers t in [64c+1, min(64c+64, 4095)]

typedef __attribute__((ext_vector_type(2))) float f32x2;

__device__ __forceinline__ float f3(float a, float b, float c) {
  return fmaxf(fmaxf(a, b), c);  // v_max3_f32
}

// scalar max over m[64] (crf_bp). fp32 max returns an input bitwise, so ANY
// tree shape (incl. fwd's packed 4-group butterfly) gives identical states.
__device__ __forceinline__ float tree64(const float* m) {
  float t[22];
#pragma unroll
  for (int i = 0; i < 21; ++i) t[i] = f3(m[3 * i], m[3 * i + 1], m[3 * i + 2]);
  t[21] = m[63];
#pragma unroll
  for (int i = 0; i < 7; ++i) t[i] = f3(t[3 * i], t[3 * i + 1], t[3 * i + 2]);
  t[7] = t[21];
  t[0] = f3(t[0], t[1], t[2]);
  t[1] = f3(t[3], t[4], t[5]);
  t[2] = t[6];
  t[3] = t[7];
  t[0] = f3(t[0], t[1], t[2]);
  return fmaxf(t[0], t[3]);
}

__device__ __forceinline__ f32x2 vmax2(f32x2 a, f32x2 b) {
  return __builtin_elementwise_max(a, b);  // v_pk_max_f32 (bit-exact)
}
__device__ __forceinline__ f32x2 f3p(f32x2 a, f32x2 b, f32x2 c) {
  return vmax2(vmax2(a, b), c);
}
// packed max over x[16] (two j's at once), depth 3
__device__ __forceinline__ f32x2 tree16p(const f32x2* x) {
  f32x2 y0 = f3p(x[0], x[1], x[2]);
  f32x2 y1 = f3p(x[3], x[4], x[5]);
  f32x2 y2 = f3p(x[6], x[7], x[8]);
  f32x2 y3 = f3p(x[9], x[10], x[11]);
  f32x2 y4 = f3p(x[12], x[13], x[14]);
  return vmax2(f3p(y0, y1, y2), f3p(y3, y4, x[15]));
}
__device__ __forceinline__ f32x2 shflx(f32x2 v, int mask) {
  f32x2 r;
  r.x = __shfl_xor(v.x, mask, 64);
  r.y = __shfl_xor(v.y, mask, 64);
  return r;
}

// ---------------------------------------------------------------------------
// Forward recurrence, 4-group split. One wave per batch, lane = (g,l),
// g=lane>>4, l=lane&15. Lane owns destination states j in {4l..4l+3} and
// source block i in [16g,16g+16):
//   - 4 ds_read_b128 per step (vs 16): state lives in 4 padded LDS replicas,
//     replica g written/read only by group g (conflict-free, no barrier —
//     single wave, in-order LDS).
//   - packed f32x2 adds + max-tree (v_pk_*, bit-exact IEEE).
//   - 2-stage shfl_xor(16,32) butterfly combines the 4 group-partials.
// Rounds 3-8 proved ~900 cyc/step is the write->16-read->64add->tree64
// critical path, independent of trans residency; this attacks each term.
// ---------------------------------------------------------------------------
__global__ __launch_bounds__(64, 1) void crf_fwd(
    const float* __restrict__ pot, const float* __restrict__ trans,
    float* __restrict__ cp, float* __restrict__ fin) {
  const int b = blockIdx.x;
  const int lane = threadIdx.x;
  const int g = lane >> 4;
  const int l = lane & 15;
  __shared__ float4 smr[4][17];  // 4 state replicas, padded (bank-clean)

  // trans fragment: tc2[i'][p] = {T[16g+i'][4l+2p], T[16g+i'][4l+2p+1]}
  f32x2 tc2[16][2];
#pragma unroll
  for (int i = 0; i < 16; ++i) {
#pragma unroll
    for (int p = 0; p < 2; ++p) {
      tc2[i][p].x = trans[(16 * g + i) * KS + 4 * l + 2 * p];
      tc2[i][p].y = trans[(16 * g + i) * KS + 4 * l + 2 * p + 1];
    }
  }

  const float* pb = pot + (size_t)b * TLEN * KS;  // batch base
  float* cpb = cp + (size_t)b * NCHUNK * KS;

  // init: s4 = states for j in 4l..4l+3 at t=0
  float4 s4 = *(const float4*)(pb + 4 * l);
  smr[g][l] = s4;
  if (g == 0) *(float4*)(cpb + 4 * l) = s4;

  // emission prefetch ring: one dwordx4 per step (this lane's 4 js)
  float4 ef[4];
#pragma unroll
  for (int q = 0; q < 4; ++q)
    ef[q] = *(const float4*)(pb + (size_t)(1 + q) * KS + 4 * l);

#pragma unroll 4
  for (int t = 1; t < TLEN; ++t) {
    float4 emit = ef[(t - 1) & 3];
    int tp = t + 4;
    tp = tp > TLEN - 1 ? TLEN - 1 : tp;
    ef[(t - 1) & 3] = *(const float4*)(pb + (size_t)tp * KS + 4 * l);

    // read this group's 16 source states from its replica (4 b128, clean)
    float4 sv[4];
#pragma unroll
    for (int q = 0; q < 4; ++q) sv[q] = smr[g][4 * g + q];

    // packed adds: m[p][i'] = s_i' + T[i'][j-pair p]
    f32x2 m0[16], m1[16];
#pragma unroll
    for (int q = 0; q < 4; ++q) {
      float si[4] = {sv[q].x, sv[q].y, sv[q].z, sv[q].w};
#pragma unroll
      for (int r = 0; r < 4; ++r) {
        f32x2 sp;
        sp.x = si[r];
        sp.y = si[r];
        m0[4 * q + r] = sp + tc2[4 * q + r][0];
        m1[4 * q + r] = sp + tc2[4 * q + r][1];
      }
    }
    // per-group partial max over 16 sources (packed, depth 3)
    f32x2 r0 = tree16p(m0);
    f32x2 r1 = tree16p(m1);

    // butterfly across groups: ^16 then ^32 -> full max over 64 sources
    r0 = vmax2(r0, shflx(r0, 16));
    r1 = vmax2(r1, shflx(r1, 16));
    r0 = vmax2(r0, shflx(r0, 32));
    r1 = vmax2(r1, shflx(r1, 32));

    s4.x = r0.x + emit.x;
    s4.y = r0.y + emit.y;
    s4.z = r1.x + emit.z;
    s4.w = r1.y + emit.w;

    smr[g][l] = s4;  // replica write (in-order LDS, next reads see it)
    if ((t & 63) == 0 && g == 0)
      *(float4*)(cpb + (size_t)(t >> 6) * KS + 4 * l) = s4;
  }
  if (g == 0) *(float4*)(fin + (size_t)b * KS + 4 * l) = s4;
}

// ---------------------------------------------------------------------------
// Backpointer reconstruction (r7 version — NO trans pinning: r8 proved the
// pin cuts occupancy and regresses this TLP-hidden kernel by ~120 us).
// Recomputes states from checkpoints (bit-identical), derives bp[t][j], and
// fuses the speculative chunk-map chase via ds_bpermute.
// ---------------------------------------------------------------------------
__global__ __launch_bounds__(64) void crf_bp(
    const float* __restrict__ pot, const float* __restrict__ trans,
    const float* __restrict__ cp, unsigned char* __restrict__ bp,
    unsigned char* __restrict__ map) {
  const int b = blockIdx.x;
  const int ch = blockIdx.y;
  const int j = threadIdx.x;
  __shared__ float4 sm4[KS / 4];
  float* sm = (float*)sm4;

  float c[KS];
#pragma unroll
  for (int i = 0; i < KS; ++i) c[i] = trans[i * KS + j];

  float s = cp[((size_t)b * NCHUNK + ch) * KS + j];
  const int t0 = ch * 64;
  const int hi = min(t0 + 64, TLEN - 1);
  const float* pb = pot + (size_t)b * TLEN * KS + j;
  unsigned char* bpb = bp + (size_t)b * TLEN * KS + j;

  sm[j] = s;
  int tag = j;  // forward-composed backward map
  float emit = pb[(size_t)(t0 + 1) * KS];
  for (int t = t0 + 1; t <= hi; ++t) {
    float emit_next = pb[(size_t)min(t + 1, TLEN - 1) * KS];

    float m[KS];
#pragma unroll
    for (int q = 0; q < KS / 4; ++q) {
      float4 v = sm4[q];
      m[4 * q + 0] = v.x + c[4 * q + 0];
      m[4 * q + 1] = v.y + c[4 * q + 1];
      m[4 * q + 2] = v.z + c[4 * q + 2];
      m[4 * q + 3] = v.w + c[4 * q + 3];
    }
    float best = tree64(m);

    // first-occurrence argmax: descending exact-equality scan
    int bi = 63;
#pragma unroll
    for (int i = 62; i >= 0; --i) bi = (m[i] == best) ? i : bi;

    bpb[(size_t)t * KS] = (unsigned char)bi;
    s = best + emit;
    sm[j] = s;
    emit = emit_next;

    tag = __builtin_amdgcn_ds_bpermute(bi << 2, tag);
  }
  map[((size_t)b * NCHUNK + ch) * KS + j] = (unsigned char)tag;
}

// ---------------------------------------------------------------------------
// Compose chunk maps per batch; final-state argmax (first-occurrence, >).
// ---------------------------------------------------------------------------
__global__ void crf_compose(const unsigned char* __restrict__ map,
                            const float* __restrict__ fin,
                            unsigned char* __restrict__ e,
                            int* __restrict__ tags_out) {
  const int b = blockIdx.x * blockDim.x + threadIdx.x;
  if (b >= BATCH) return;
  const float* fb = fin + (size_t)b * KS;
  float best = fb[0];
  int cur = 0;
  for (int i = 1; i < KS; ++i) {
    float v = fb[i];
    if (v > best) { best = v; cur = i; }
  }
  tags_out[(size_t)b * TLEN + (TLEN - 1)] = cur;
  for (int ch = NCHUNK - 1; ch >= 0; --ch) {
    e[(size_t)b * NCHUNK + ch] = (unsigned char)cur;
    cur = map[((size_t)b * NCHUNK + ch) * KS + cur];
  }
}

// ---------------------------------------------------------------------------
// Extract per-chunk paths from known entering tags (parallel over B*NCHUNK).
// ---------------------------------------------------------------------------
__global__ void crf_extract(const unsigned char* __restrict__ bp,
                            const unsigned char* __restrict__ e,
                            int* __restrict__ tags_out) {
  const int idx = blockIdx.x * blockDim.x + threadIdx.x;  // b*NCHUNK + c
  if (idx >= BATCH * NCHUNK) return;
  const int b = idx >> 6;
  const int c = idx & (NCHUNK - 1);
  const int lo = 64 * c + 1;
  const int hi = min(64 * c + 64, TLEN - 1);
  const unsigned char* bpb = bp + (size_t)b * TLEN * KS;
  int* to = tags_out + (size_t)b * TLEN;
  int tag = e[(size_t)b * NCHUNK + c];
  for (int t = hi; t >= lo; --t) {
    tag = bpb[(size_t)t * KS + tag];
    to[t - 1] = tag;
  }
}

// ---------------------------------------------------------------------------
// Sequence lengths = sum(mask) per batch.
// ---------------------------------------------------------------------------
__global__ __launch_bounds__(64) void crf_lens(const int* __restrict__ mask,
                                               int* __restrict__ out) {
  const int b = blockIdx.x;
  const int l = threadIdx.x;
  const int* mb = mask + (size_t)b * TLEN;
  int sum = 0;
  for (int t = l; t < TLEN; t += 64) sum += mb[t];
#pragma unroll
  for (int off = 32; off > 0; off >>= 1) sum += __shfl_down(sum, off, 64);
  if (l == 0) out[b] = sum;
}

extern "C" void kernel_launch(void* const* d_in, const int* in_sizes, int n_in,
                              void* d_out, int out_size, void* d_ws,
                              size_t ws_size, hipStream_t stream) {
  const float* pot = (const float*)d_in[0];    // (128, 4096, 64) fp32
  const float* trans = (const float*)d_in[1];  // (64, 64) fp32
  const int* mask = (const int*)d_in[2];       // (128, 4096) int32

  int* out = (int*)d_out;  // [tags: 128*4096][lens: 128]
  int* tags_out = out;
  int* lens_out = out + (size_t)BATCH * TLEN;

  // workspace layout
  char* w = (char*)d_ws;
  unsigned char* bp = (unsigned char*)w;                     // 33,554,432 B
  float* cp = (float*)(bp + (size_t)BATCH * TLEN * KS);      //  2,097,152 B
  float* fin = cp + (size_t)BATCH * NCHUNK * KS;             //     32,768 B
  unsigned char* map = (unsigned char*)(fin + (size_t)BATCH * KS);  // 524,288 B
  unsigned char* e = map + (size_t)BATCH * NCHUNK * KS;      //      8,192 B

  crf_fwd<<<BATCH, 64, 0, stream>>>(pot, trans, cp, fin);
  crf_lens<<<BATCH, 64, 0, stream>>>(mask, lens_out);
  crf_bp<<<dim3(BATCH, NCHUNK), 64, 0, stream>>>(pot, trans, cp, bp, map);
  crf_compose<<<1, BATCH, 0, stream>>>(map, fin, e, tags_out);
  crf_extract<<<(BATCH * NCHUNK + 255) / 256, 256, 0, stream>>>(bp, e, tags_out);
}